// Round 1
// baseline (52.695 us; speedup 1.0000x reference)
//
#include <hip/hip_runtime.h>
#include <math.h>

#define B 8
#define G 64
#define S 256
#define DIM 41
#define ET 128
#define H 8
#define EK 16
#define NH 127
#define HD (H*DIM)  // 328

// ---------------- K2: k projection: kp[b,s,:] = key[b,s,:] @ Wk + bk ----------------
__global__ __launch_bounds__(128) void kproj_kernel(const float* __restrict__ key,
                                                    const float* __restrict__ Wk,
                                                    const float* __restrict__ bk,
                                                    float* __restrict__ kp) {
    __shared__ float krow[DIM];
    const int row = blockIdx.x;      // b*S + s
    const int j = threadIdx.x;       // 0..127
    if (j < DIM) krow[j] = key[row * DIM + j];
    __syncthreads();
    float acc = bk[j];
#pragma unroll
    for (int i = 0; i < DIM; ++i) acc = fmaf(krow[i], Wk[i * ET + j], acc);
    kp[row * ET + j] = acc;
}

// ---------------- K3: fused qproj + scores + masked softmax + PV + out proj ----------------
// one block per (b,g), 512 threads (8 waves)
__global__ __launch_bounds__(512) void fused_kernel(const float* __restrict__ query,
                                                    const float* __restrict__ value,
                                                    const float* __restrict__ mask,
                                                    const float* __restrict__ qt,
                                                    const float* __restrict__ tt,
                                                    const float* __restrict__ stride_in,
                                                    const float* __restrict__ Wq,
                                                    const float* __restrict__ bq,
                                                    const float* __restrict__ Wo,
                                                    const float* __restrict__ bo,
                                                    const float* __restrict__ Wr,
                                                    const float* __restrict__ br,
                                                    const float* __restrict__ kp,
                                                    float* __restrict__ out) {
    __shared__ float qin[ET];          // raw query row
    __shared__ float qrow[ET];         // projected q row
    __shared__ float se[H][S];         // scores, then exp(scores - max)
    __shared__ float vlds[S * DIM];    // value[b] staged
    __shared__ unsigned int mbits[S * 2];  // mask bitmask per s (41 bits in 2 words)
    __shared__ float ttl[S];           // tt[b,:]
    __shared__ float strd[DIM];        // sigmoid stride
    __shared__ float xrow[HD];         // x row before out-proj
    __shared__ float Mbuf[H];          // per-head max
    __shared__ float qtg;

    const int bid = blockIdx.x;
    const int b = bid / G, g = bid % G;
    const int tid = threadIdx.x;

    // ---------------- P0: stage inputs ----------------
    if (tid == 0) qtg = qt[g];
    if (tid < ET) qin[tid] = query[(b * G + g) * ET + tid];
    if (tid >= ET && tid < ET + DIM) {
        const int d = tid - ET;
        float a = br[d];
        for (int i = 0; i < DIM; ++i) a = fmaf(stride_in[i], Wr[i * DIM + d], a);
        strd[d] = 1.0f / (1.0f + expf(-a));
    }
    if (tid >= 192 && tid < 192 + S) {
        const int s = tid - 192;
        ttl[s] = tt[b * S + s];
    }
    // mask -> bitmask: 512 words, one per thread
    {
        const int w = tid;              // 0..511
        const int s = w >> 1, half = w & 1;
        const int dbase = half * 32;
        const int nd = half ? (DIM - 32) : 32;
        const float* mrow = mask + (size_t)(b * S + s) * DIM + dbase;
        unsigned int bits = 0u;
        for (int j = 0; j < nd; ++j)
            if (mrow[j] != 0.0f) bits |= (1u << j);
        mbits[w] = bits;
    }
    for (int idx = tid; idx < S * DIM; idx += 512) vlds[idx] = value[b * S * DIM + idx];
    __syncthreads();

    // ---------------- P1: q projection ----------------
    if (tid < ET) {
        const int j = tid;
        float a = bq[j];
#pragma unroll 8
        for (int i = 0; i < ET; ++i) a = fmaf(qin[i], Wq[i * ET + j], a);
        qrow[j] = a;
    }
    __syncthreads();

    // ---------------- P2: scores[h][s] = q[h,:].k[s,h,:] / 4 ----------------
    {
        const int s = tid & (S - 1);
        const int hh = tid >> 8;        // 0 or 1 -> heads hh*4 .. hh*4+3
        const float* krow = kp + (size_t)(b * S + s) * ET;
#pragma unroll
        for (int h4 = 0; h4 < 4; ++h4) {
            const int h = hh * 4 + h4;
            float a = 0.f;
#pragma unroll
            for (int e = 0; e < EK; ++e) a = fmaf(qrow[h * EK + e], krow[h * EK + e], a);
            se[h][s] = a * 0.25f;       // 1/sqrt(EK), EK=16
        }
    }
    __syncthreads();

    // ---------------- P3: per-head max over s (wave w handles h=w) ----------------
    {
        const int w = tid >> 6, l = tid & 63;
        float m = fmaxf(fmaxf(se[w][l], se[w][l + 64]),
                        fmaxf(se[w][l + 128], se[w][l + 192]));
        for (int off = 32; off; off >>= 1) m = fmaxf(m, __shfl_down(m, off, 64));
        if (l == 0) Mbuf[w] = m;
    }
    __syncthreads();

    // ---------------- P4: e = exp(score - max) ----------------
    {
        const int s = tid & (S - 1);
        const int hh = tid >> 8;
#pragma unroll
        for (int h4 = 0; h4 < 4; ++h4) {
            const int h = hh * 4 + h4;
            se[h][s] = __expf(se[h][s] - Mbuf[h]);
        }
    }
    __syncthreads();

    // ---------------- P5: masked weighted sum over s, per (h,d) ----------------
    if (tid < HD) {
        const int h = tid / DIM, d = tid % DIM;
        const float sd = strd[d];
        const float lo = qtg - sd, hi = qtg + sd;
        const unsigned int sel = (unsigned)(d >> 5);
        const unsigned int sh = (unsigned)(d & 31);
        float Ssum = 0.f, acc = 0.f, vsum = 0.f;
        for (int s = 0; s < S; ++s) {
            const float e = se[h][s];
            const float v = vlds[s * DIM + d];
            const float t = ttl[s];
            const bool pred = (t >= lo) & (t <= hi) & (((mbits[s * 2 + sel] >> sh) & 1u) != 0u);
            const float w = pred ? e : 0.f;
            Ssum += w;
            acc = fmaf(w, v, acc);
            vsum += v;  // for the all-masked uniform-softmax case
        }
        xrow[tid] = (Ssum != 0.f) ? (acc / Ssum) : (vsum * (1.0f / S));
    }
    __syncthreads();

    // ---------------- P6: out = xrow @ Wo + bo ----------------
    if (tid < NH) {
        const int n = tid;
        float a = bo[n];
        for (int i = 0; i < HD; ++i) a = fmaf(xrow[i], Wo[i * NH + n], a);
        out[(size_t)(b * G + g) * NH + n] = a;
    }
}

extern "C" void kernel_launch(void* const* d_in, const int* in_sizes, int n_in,
                              void* d_out, int out_size, void* d_ws, size_t ws_size,
                              hipStream_t stream) {
    const float* query     = (const float*)d_in[0];
    const float* key       = (const float*)d_in[1];
    const float* value     = (const float*)d_in[2];
    const float* mask      = (const float*)d_in[3];
    const float* qt        = (const float*)d_in[4];
    const float* tt        = (const float*)d_in[5];
    const float* stride_in = (const float*)d_in[6];
    const float* Wq        = (const float*)d_in[7];
    const float* bq        = (const float*)d_in[8];
    const float* Wk        = (const float*)d_in[9];
    const float* bk        = (const float*)d_in[10];
    const float* Wo        = (const float*)d_in[11];
    const float* bo        = (const float*)d_in[12];
    const float* Wr        = (const float*)d_in[13];
    const float* br        = (const float*)d_in[14];
    float* out = (float*)d_out;
    float* kp = (float*)d_ws;  // B*S*ET f32 = 1 MiB scratch

    kproj_kernel<<<B * S, 128, 0, stream>>>(key, Wk, bk, kp);
    fused_kernel<<<B * G, 512, 0, stream>>>(query, value, mask, qt, tt, stride_in,
                                            Wq, bq, Wo, bo, Wr, br, kp, out);
}

// Round 2
// 48.015 us; speedup vs baseline: 1.0975x; 1.0975x over previous
//
#include <hip/hip_runtime.h>
#include <math.h>

#define B 8
#define G 64
#define S 256
#define DIM 41
#define ET 128
#define H 8
#define EK 16
#define NH 127
#define HD (H*DIM)  // 328

// ---------------- K1: k projection: kp[b,s,:] = key[b,s,:] @ Wk + bk ----------------
__global__ __launch_bounds__(128) void kproj_kernel(const float* __restrict__ key,
                                                    const float* __restrict__ Wk,
                                                    const float* __restrict__ bk,
                                                    float* __restrict__ kp) {
    __shared__ float krow[DIM];
    const int row = blockIdx.x;      // b*S + s
    const int j = threadIdx.x;       // 0..127
    if (j < DIM) krow[j] = key[row * DIM + j];
    __syncthreads();
    float acc = bk[j];
#pragma unroll
    for (int i = 0; i < DIM; ++i) acc = fmaf(krow[i], Wk[i * ET + j], acc);
    kp[row * ET + j] = acc;
}

// ---------------- K2: q projection: qp[bg,:] = query[bg,:] @ Wq + bq ----------------
__global__ __launch_bounds__(128) void qproj_kernel(const float* __restrict__ query,
                                                    const float* __restrict__ Wq,
                                                    const float* __restrict__ bq,
                                                    float* __restrict__ qp) {
    __shared__ float qin[ET];
    const int row = blockIdx.x;      // b*G + g
    const int j = threadIdx.x;       // 0..127
    qin[j] = query[row * ET + j];
    __syncthreads();
    float a0 = 0.f, a1 = 0.f, a2 = 0.f, a3 = 0.f;
#pragma unroll 8
    for (int i = 0; i < ET; i += 4) {
        a0 = fmaf(qin[i + 0], Wq[(i + 0) * ET + j], a0);
        a1 = fmaf(qin[i + 1], Wq[(i + 1) * ET + j], a1);
        a2 = fmaf(qin[i + 2], Wq[(i + 2) * ET + j], a2);
        a3 = fmaf(qin[i + 3], Wq[(i + 3) * ET + j], a3);
    }
    qp[row * ET + j] = bq[j] + ((a0 + a1) + (a2 + a3));
}

// ---------------- K3: embits[bg][s*2+w]: (window AND mask) bit per (s,d) ----------------
__global__ __launch_bounds__(256) void embits_kernel(const float* __restrict__ mask,
                                                     const float* __restrict__ qt,
                                                     const float* __restrict__ tt,
                                                     const float* __restrict__ stride_in,
                                                     const float* __restrict__ Wr,
                                                     const float* __restrict__ br,
                                                     unsigned int* __restrict__ embits) {
    __shared__ float strd[DIM];
    const int bid = blockIdx.x;      // b*G + g
    const int b = bid / G, g = bid % G;
    const int tid = threadIdx.x;     // = s
    if (tid < DIM) {
        float a = br[tid];
        for (int i = 0; i < DIM; ++i) a = fmaf(stride_in[i], Wr[i * DIM + tid], a);
        strd[tid] = 1.0f / (1.0f + expf(-a));
    }
    __syncthreads();
    const float qtg = qt[g];
    const float t = tt[b * S + tid];
    const float* mrow = mask + (size_t)(b * S + tid) * DIM;
    unsigned int w0 = 0u, w1 = 0u;
#pragma unroll
    for (int d = 0; d < DIM; ++d) {
        const float sd = strd[d];
        const bool ok = (t >= qtg - sd) & (t <= qtg + sd) & (mrow[d] != 0.0f);
        if (d < 32) w0 |= ((unsigned)ok) << d;
        else        w1 |= ((unsigned)ok) << (d - 32);
    }
    embits[(size_t)bid * (S * 2) + tid * 2 + 0] = w0;
    embits[(size_t)bid * (S * 2) + tid * 2 + 1] = w1;
}

// ---------------- K4: attention core, one block per (b,g,h) ----------------
__global__ __launch_bounds__(128) void attn_kernel(const float* __restrict__ qp,
                                                   const float* __restrict__ kp,
                                                   const float* __restrict__ value,
                                                   const unsigned int* __restrict__ embits,
                                                   float* __restrict__ x) {
    __shared__ float se[S];              // exp(score - M)
    __shared__ unsigned int eb[S * 2];   // effective mask bits
    __shared__ float qv[EK];
    __shared__ float red[2];
    __shared__ float ps[2][DIM];
    __shared__ float pa[2][DIM];

    const int bid = blockIdx.x;          // ((b*G+g)*H + h)
    const int h = bid & (H - 1);
    const int bg = bid >> 3;             // b*G + g
    const int b = bg >> 6;               // G = 64
    const int tid = threadIdx.x;

    // stage embits (512 words)
#pragma unroll
    for (int i = 0; i < 4; ++i) eb[tid + i * 128] = embits[(size_t)bg * (S * 2) + tid + i * 128];
    if (tid < EK) qv[tid] = qp[(size_t)bg * ET + h * EK + tid];
    __syncthreads();

    // scores: 2 s per thread
    float sc[2];
#pragma unroll
    for (int ss = 0; ss < 2; ++ss) {
        const int s = tid + ss * 128;
        const float4* k4 = reinterpret_cast<const float4*>(kp + ((size_t)(b * S + s) * ET + h * EK));
        float a = 0.f;
#pragma unroll
        for (int q4 = 0; q4 < 4; ++q4) {
            const float4 kv = k4[q4];
            a = fmaf(qv[q4 * 4 + 0], kv.x, a);
            a = fmaf(qv[q4 * 4 + 1], kv.y, a);
            a = fmaf(qv[q4 * 4 + 2], kv.z, a);
            a = fmaf(qv[q4 * 4 + 3], kv.w, a);
        }
        sc[ss] = a * 0.25f;              // 1/sqrt(EK)
    }
    // per-(b,g,h) max over all s
    float m = fmaxf(sc[0], sc[1]);
#pragma unroll
    for (int off = 32; off; off >>= 1) m = fmaxf(m, __shfl_down(m, off, 64));
    if ((tid & 63) == 0) red[tid >> 6] = m;
    __syncthreads();
    const float M = fmaxf(red[0], red[1]);
    se[tid]       = __expf(sc[0] - M);
    se[tid + 128] = __expf(sc[1] - M);
    __syncthreads();

    // masked weighted sum: wave wv covers s in [wv*128, wv*128+128), lanes = d
    const int lane = tid & 63, wv = tid >> 6;
    if (lane < DIM) {
        const int d = lane;
        const unsigned int sel = (unsigned)(d >> 5);
        const unsigned int sh = (unsigned)(d & 31);
        const float* vb = value + (size_t)b * S * DIM + d;
        const int s0 = wv * 128;
        float Ssum = 0.f, acc = 0.f;
#pragma unroll 4
        for (int i = 0; i < 128; ++i) {
            const int s = s0 + i;
            const float e = se[s];
            const unsigned int bit = (eb[s * 2 + sel] >> sh) & 1u;
            const float v = vb[(size_t)s * DIM];
            const float w = bit ? e : 0.f;
            Ssum += w;
            acc = fmaf(w, v, acc);
        }
        ps[wv][d] = Ssum;
        pa[wv][d] = acc;
    }
    __syncthreads();

    if (tid < DIM) {
        const float St = ps[0][tid] + ps[1][tid];
        const float At = pa[0][tid] + pa[1][tid];
        float r;
        if (St != 0.f) {
            r = At / St;
        } else {
            // all-masked column: softmax is uniform 1/S (never taken in practice)
            float vs = 0.f;
            const float* vb = value + (size_t)b * S * DIM + tid;
            for (int s = 0; s < S; ++s) vs += vb[(size_t)s * DIM];
            r = vs * (1.0f / S);
        }
        x[(size_t)bg * HD + h * DIM + tid] = r;
    }
}

// ---------------- K5: out = x @ Wo + bo ----------------
__global__ __launch_bounds__(128) void outproj_kernel(const float* __restrict__ x,
                                                      const float* __restrict__ Wo,
                                                      const float* __restrict__ bo,
                                                      float* __restrict__ out) {
    __shared__ float xr[HD];
    const int bg = blockIdx.x;
    const int tid = threadIdx.x;
    for (int i = tid; i < HD; i += 128) xr[i] = x[(size_t)bg * HD + i];
    __syncthreads();
    if (tid < NH) {
        float a0 = 0.f, a1 = 0.f, a2 = 0.f, a3 = 0.f;
#pragma unroll 4
        for (int i = 0; i < HD; i += 4) {  // HD = 328 = 4*82
            a0 = fmaf(xr[i + 0], Wo[(size_t)(i + 0) * NH + tid], a0);
            a1 = fmaf(xr[i + 1], Wo[(size_t)(i + 1) * NH + tid], a1);
            a2 = fmaf(xr[i + 2], Wo[(size_t)(i + 2) * NH + tid], a2);
            a3 = fmaf(xr[i + 3], Wo[(size_t)(i + 3) * NH + tid], a3);
        }
        out[(size_t)bg * NH + tid] = bo[tid] + ((a0 + a1) + (a2 + a3));
    }
}

extern "C" void kernel_launch(void* const* d_in, const int* in_sizes, int n_in,
                              void* d_out, int out_size, void* d_ws, size_t ws_size,
                              hipStream_t stream) {
    const float* query     = (const float*)d_in[0];
    const float* key       = (const float*)d_in[1];
    const float* value     = (const float*)d_in[2];
    const float* mask      = (const float*)d_in[3];
    const float* qt        = (const float*)d_in[4];
    const float* tt        = (const float*)d_in[5];
    const float* stride_in = (const float*)d_in[6];
    const float* Wq        = (const float*)d_in[7];
    const float* bq        = (const float*)d_in[8];
    const float* Wk        = (const float*)d_in[9];
    const float* bk        = (const float*)d_in[10];
    const float* Wo        = (const float*)d_in[11];
    const float* bo        = (const float*)d_in[12];
    const float* Wr        = (const float*)d_in[13];
    const float* br        = (const float*)d_in[14];
    float* out = (float*)d_out;

    // workspace layout (floats/uints)
    float* kp = (float*)d_ws;                        // B*S*ET      = 262144 f32
    float* qp = kp + (size_t)B * S * ET;             // B*G*ET      = 65536 f32
    unsigned int* embits = (unsigned int*)(qp + (size_t)B * G * ET);  // B*G*S*2 = 262144 u32
    float* x = (float*)(embits + (size_t)B * G * S * 2);              // B*G*HD  = 167936 f32

    kproj_kernel<<<B * S, 128, 0, stream>>>(key, Wk, bk, kp);
    qproj_kernel<<<B * G, 128, 0, stream>>>(query, Wq, bq, qp);
    embits_kernel<<<B * G, 256, 0, stream>>>(mask, qt, tt, stride_in, Wr, br, embits);
    attn_kernel<<<B * G * H, 128, 0, stream>>>(qp, kp, value, embits, x);
    outproj_kernel<<<B * G, 128, 0, stream>>>(x, Wo, bo, out);
}

// Round 3
// 34.583 us; speedup vs baseline: 1.5237x; 1.3884x over previous
//
#include <hip/hip_runtime.h>
#include <math.h>

#define B 8
#define G 64
#define S 256
#define DIM 41
#define ET 128
#define H 8
#define EK 16
#define NH 127
#define HD (H*DIM)  // 328

// ---------------- K1 "prep": kproj->kpT4, qproj, embitsT ----------------
// grid 1792 x 256:
//   blocks [0,1024): kproj, 2 rows each       (2048 rows of key)
//   blocks [1024,1280): qproj, 2 rows each    (512 rows of query)
//   blocks [1280,1792): embitsT per (b,g)     (window AND mask bits, d-major)
__global__ __launch_bounds__(256) void prep_kernel(const float* __restrict__ key,
                                                   const float* __restrict__ Wk,
                                                   const float* __restrict__ bk,
                                                   const float* __restrict__ query,
                                                   const float* __restrict__ Wq,
                                                   const float* __restrict__ bq,
                                                   const float* __restrict__ mask,
                                                   const float* __restrict__ qt,
                                                   const float* __restrict__ tt,
                                                   const float* __restrict__ stride_in,
                                                   const float* __restrict__ Wr,
                                                   const float* __restrict__ br,
                                                   float* __restrict__ kpT,
                                                   float* __restrict__ qp,
                                                   unsigned int* __restrict__ embitsT) {
    const int bid = blockIdx.x;
    const int tid = threadIdx.x;

    if (bid < 1024) {
        // ---- kproj: rows r0 = bid*2, r0+1. kpT layout: float at
        // b*32768 + (j>>2)*1024 + s*4 + (j&3)  (i.e. float4 [b][h*4+e4][s])
        __shared__ float klds[2][48];
        const int half = tid >> 7;          // 0/1 -> row
        const int j = tid & 127;            // output col 0..127
        const int row = bid * 2 + half;     // b*S + s
        if (j < DIM) klds[half][j] = key[row * DIM + j];
        __syncthreads();
        float acc = bk[j];
#pragma unroll
        for (int i = 0; i < DIM; ++i) acc = fmaf(klds[half][i], Wk[i * ET + j], acc);
        const int b = row >> 8, s = row & 255;
        kpT[b * 32768 + (j >> 2) * 1024 + s * 4 + (j & 3)] = acc;
    } else if (bid < 1280) {
        // ---- qproj: rows (bid-1024)*2 + half
        __shared__ float qlds[2][ET];
        const int base = (bid - 1024) * 2;
        ((float*)qlds)[tid] = query[base * ET + tid];   // 256 consecutive floats
        __syncthreads();
        const int half = tid >> 7;
        const int j = tid & 127;
        float a0 = 0.f, a1 = 0.f, a2 = 0.f, a3 = 0.f;
#pragma unroll 8
        for (int i = 0; i < ET; i += 4) {
            a0 = fmaf(qlds[half][i + 0], Wq[(i + 0) * ET + j], a0);
            a1 = fmaf(qlds[half][i + 1], Wq[(i + 1) * ET + j], a1);
            a2 = fmaf(qlds[half][i + 2], Wq[(i + 2) * ET + j], a2);
            a3 = fmaf(qlds[half][i + 3], Wq[(i + 3) * ET + j], a3);
        }
        qp[(base + half) * ET + j] = bq[j] + ((a0 + a1) + (a2 + a3));
    } else {
        // ---- embitsT per (b,g): bit(s,d) = window & mask, stored d-major:
        // embitsT[bg*328 + d*8 + (s>>5)], bit (s&31)
        __shared__ float strd[DIM];
        const int bg = bid - 1280;
        const int b = bg >> 6, g = bg & 63;
        if (tid < DIM) {
            float a = br[tid];
            for (int i = 0; i < DIM; ++i) a = fmaf(stride_in[i], Wr[i * DIM + tid], a);
            strd[tid] = 1.0f / (1.0f + expf(-a));
        }
        // per-thread: s = tid; build mask bit-words for this row
        const int s = tid;
        const float t = tt[b * S + s];
        const float qtg = qt[g];
        const float* mrow = mask + (size_t)(b * S + s) * DIM;
        unsigned int m0 = 0u, m1 = 0u;
#pragma unroll
        for (int d = 0; d < DIM; ++d) {
            const bool mb = (mrow[d] != 0.0f);
            if (d < 32) m0 |= ((unsigned)mb) << d;
            else        m1 |= ((unsigned)mb) << (d - 32);
        }
        __syncthreads();
        const int w = tid >> 6;             // wave index 0..3
        unsigned int* outp = embitsT + (size_t)bg * (DIM * 8);
#pragma unroll
        for (int d = 0; d < DIM; ++d) {
            const float sd = strd[d];
            const float lo = qtg - sd, hi = qtg + sd;
            const unsigned int mbit = (d < 32) ? ((m0 >> d) & 1u) : ((m1 >> (d - 32)) & 1u);
            const int ok = (t >= lo) & (t <= hi) & (int)mbit;
            const unsigned long long bal = __ballot(ok);
            if ((tid & 63) == 0) {
                outp[d * 8 + 2 * w]     = (unsigned int)bal;
                outp[d * 8 + 2 * w + 1] = (unsigned int)(bal >> 32);
            }
        }
    }
}

// ---------------- K2 "main": scores + softmax + masked PV + outproj, per (b,g) ----------------
__global__ __launch_bounds__(512) void main_kernel(const float* __restrict__ kpT,
                                                   const float* __restrict__ qp,
                                                   const unsigned int* __restrict__ embitsT,
                                                   const float* __restrict__ value,
                                                   const float* __restrict__ Wo,
                                                   const float* __restrict__ bo,
                                                   float* __restrict__ out) {
    __shared__ float se[H][S];       // scores then exp(score-M)
    __shared__ float vlds[S * DIM];  // value[b]
    __shared__ float qv[ET];
    __shared__ float Mb[H];
    __shared__ float xrow[HD];
    __shared__ float po[4][128];

    const int bg = blockIdx.x;
    const int b = bg >> 6;
    const int tid = threadIdx.x;

    // (h,d) assignment for the weighted phase; preload bit words early (global, no deps)
    const int hd_h = tid / DIM;
    const int hd_d = tid - hd_h * DIM;
    unsigned int ebw0 = 0, ebw1 = 0, ebw2 = 0, ebw3 = 0, ebw4 = 0, ebw5 = 0, ebw6 = 0, ebw7 = 0;
    if (tid < HD) {
        const uint4* p = reinterpret_cast<const uint4*>(embitsT + (size_t)bg * (DIM * 8) + hd_d * 8);
        const uint4 e0 = p[0], e1 = p[1];
        ebw0 = e0.x; ebw1 = e0.y; ebw2 = e0.z; ebw3 = e0.w;
        ebw4 = e1.x; ebw5 = e1.y; ebw6 = e1.z; ebw7 = e1.w;
    }

    // stage qv + value
    if (tid < ET) qv[tid] = qp[(size_t)bg * ET + tid];
    for (int idx = tid; idx < S * DIM; idx += 512) vlds[idx] = value[(size_t)b * S * DIM + idx];
    __syncthreads();

    // scores: threads 0..255, s = tid, all 8 heads in registers
    float sc[H];
    if (tid < S) {
        const int s = tid;
        const float4* kb = reinterpret_cast<const float4*>(kpT) + (size_t)b * 8192 + s;
#pragma unroll
        for (int h = 0; h < H; ++h) {
            float a = 0.f;
#pragma unroll
            for (int e4 = 0; e4 < 4; ++e4) {
                const float4 kv = kb[(h * 4 + e4) * 256];
                a = fmaf(qv[h * EK + e4 * 4 + 0], kv.x, a);
                a = fmaf(qv[h * EK + e4 * 4 + 1], kv.y, a);
                a = fmaf(qv[h * EK + e4 * 4 + 2], kv.z, a);
                a = fmaf(qv[h * EK + e4 * 4 + 3], kv.w, a);
            }
            sc[h] = a * 0.25f;           // 1/sqrt(EK)
            se[h][s] = sc[h];
        }
    }
    __syncthreads();

    // per-head max: threads 0..255, h = tid>>5, j = tid&31
    if (tid < S) {
        const int h = tid >> 5, j = tid & 31;
        float m = se[h][j];
#pragma unroll
        for (int k = 1; k < 8; ++k) m = fmaxf(m, se[h][j + 32 * k]);
#pragma unroll
        for (int off = 16; off; off >>= 1) m = fmaxf(m, __shfl_xor(m, off, 32));
        if (j == 0) Mb[h] = m;
    }
    __syncthreads();

    // exp: threads 0..255 use their register scores
    if (tid < S) {
        const int s = tid;
#pragma unroll
        for (int h = 0; h < H; ++h) se[h][s] = __expf(sc[h] - Mb[h]);
    }
    __syncthreads();

    // masked weighted sum: threads 0..327 -> (h,d)
    if (tid < HD) {
        const int h = hd_h, d = hd_d;
        float Ssum = 0.f, acc = 0.f;
        const unsigned int ws[8] = {ebw0, ebw1, ebw2, ebw3, ebw4, ebw5, ebw6, ebw7};
#pragma unroll
        for (int k = 0; k < 8; ++k) {
            const unsigned int wv = ws[k];
#pragma unroll 8
            for (int i = 0; i < 32; ++i) {
                const int s = k * 32 + i;
                const float e = se[h][s];
                const float v = vlds[s * DIM + d];
                const float wgt = ((wv >> i) & 1u) ? e : 0.f;
                Ssum += wgt;
                acc = fmaf(wgt, v, acc);
            }
        }
        float r;
        if (Ssum != 0.f) {
            r = acc / Ssum;
        } else {
            // all-masked column: uniform softmax -> column mean of value
            float vs = 0.f;
            for (int s = 0; s < S; ++s) vs += vlds[s * DIM + d];
            r = vs * (1.0f / S);
        }
        xrow[tid] = r;
    }
    __syncthreads();

    // out-proj: 4 i-chunks of 82, lanes n = tid&127 (n<127 active)
    {
        const int n = tid & 127, c = tid >> 7;
        if (n < NH) {
            const int i0 = c * 82;
            float a0 = 0.f, a1 = 0.f;
#pragma unroll 2
            for (int i = i0; i < i0 + 82; i += 2) {
                a0 = fmaf(xrow[i],     Wo[(size_t)i * NH + n],       a0);
                a1 = fmaf(xrow[i + 1], Wo[(size_t)(i + 1) * NH + n], a1);
            }
            po[c][n] = a0 + a1;
        }
    }
    __syncthreads();
    if (tid < NH) {
        out[(size_t)bg * NH + tid] = bo[tid] + ((po[0][tid] + po[1][tid]) + (po[2][tid] + po[3][tid]));
    }
}

extern "C" void kernel_launch(void* const* d_in, const int* in_sizes, int n_in,
                              void* d_out, int out_size, void* d_ws, size_t ws_size,
                              hipStream_t stream) {
    const float* query     = (const float*)d_in[0];
    const float* key       = (const float*)d_in[1];
    const float* value     = (const float*)d_in[2];
    const float* mask      = (const float*)d_in[3];
    const float* qt        = (const float*)d_in[4];
    const float* tt        = (const float*)d_in[5];
    const float* stride_in = (const float*)d_in[6];
    const float* Wq        = (const float*)d_in[7];
    const float* bq        = (const float*)d_in[8];
    const float* Wk        = (const float*)d_in[9];
    const float* bk        = (const float*)d_in[10];
    const float* Wo        = (const float*)d_in[11];
    const float* bo        = (const float*)d_in[12];
    const float* Wr        = (const float*)d_in[13];
    const float* br        = (const float*)d_in[14];
    float* out = (float*)d_out;

    // workspace layout
    float* kpT = (float*)d_ws;                                   // B*H*4*S*4 = 262144 f32 (1 MiB)
    float* qp = kpT + (size_t)B * H * 4 * S * 4;                 // B*G*ET    = 65536 f32
    unsigned int* embitsT = (unsigned int*)(qp + (size_t)B * G * ET);  // B*G*DIM*8 = 167936 u32

    prep_kernel<<<1792, 256, 0, stream>>>(key, Wk, bk, query, Wq, bq, mask, qt, tt,
                                          stride_in, Wr, br, kpT, qp, embitsT);
    main_kernel<<<B * G, 512, 0, stream>>>(kpT, qp, embitsT, value, Wo, bo, out);
}